// Round 6
// baseline (179.291 us; speedup 1.0000x reference)
//
#include <hip/hip_runtime.h>
#include <stdint.h>

// EfficientDet post-process: score max/argmax -> top-1000 select -> sort -> NMS.
#define A_NUM   49104
#define BATCH   8
#define NCLS    90
#define KSEL    1000
#define SCORE_T 0.05f
#define IOU_T   0.5f
#define IMG_F   512.0f

#define HBLK    12          // histogram blocks per image
#define CHUNK   4092        // 12 * 4092 = 49104 exactly

// monotonic 32-bit transform: float compare == unsigned compare
__device__ __forceinline__ uint32_t mono32(float s) {
    uint32_t u = __float_as_uint(s);
    return (u & 0x80000000u) ? ~u : (u | 0x80000000u);
}

// ---- kernel 1: per-anchor class max + argmax, mask <= T to -1.
// Also zeroes the 2-MB global top16 histogram (131072 uint4).
__global__ void score_kernel(const float* __restrict__ cls,
                             float* __restrict__ scores,
                             int* __restrict__ classes,
                             uint4* __restrict__ ghist_zero) {
    int i = blockIdx.x * blockDim.x + threadIdx.x;
    if (i < 131072) ghist_zero[i] = uint4{0, 0, 0, 0};
    const int BA = BATCH * A_NUM;
    if (i >= BA) return;
    const float* row = cls + (size_t)i * NCLS;
    float best = -1e30f; int bc = 0;
    #pragma unroll 9
    for (int c = 0; c < NCLS; c += 2) {
        float2 v = *reinterpret_cast<const float2*>(row + c);
        if (v.x > best) { best = v.x; bc = c; }
        if (v.y > best) { best = v.y; bc = c + 1; }
    }
    scores[i]  = (best > SCORE_T) ? best : -1.0f;
    classes[i] = bc;
}

// ---- kernel 2: top-16-bit histogram, 12 blocks/image, LDS pre-aggregation
__global__ void __launch_bounds__(1024) hist1_kernel(const float* __restrict__ scores,
                                                     uint32_t* __restrict__ ghist) {
    __shared__ uint32_t lh[32768];
    const int b   = blockIdx.x / HBLK;
    const int c   = blockIdx.x % HBLK;
    const int tid = threadIdx.x;
    #pragma unroll
    for (int t = tid; t < 32768; t += 1024) lh[t] = 0;
    __syncthreads();
    const float* sc = scores + (size_t)b * A_NUM;
    const int i0 = c * CHUNK;
    const int i1 = (i0 + CHUNK < A_NUM) ? i0 + CHUNK : A_NUM;
    for (int i = i0 + tid; i < i1; i += 1024) {
        uint32_t bin = mono32(sc[i]) >> 16;
        atomicAdd(&lh[bin >> 1], (bin & 1) ? 0x10000u : 1u);
    }
    __syncthreads();
    uint32_t* gh = ghist + (size_t)b * 65536;
    for (int t = tid; t < 32768; t += 1024) {
        uint32_t v = lh[t];
        if (v) {
            uint32_t lo = v & 0xFFFFu, hi = v >> 16;
            if (lo) atomicAdd(&gh[2 * t],     lo);
            if (hi) atomicAdd(&gh[2 * t + 1], hi);
        }
    }
}

// ---- kernel 3 (mega): per-image select+sort+emit, one 1024-thread block/image.
// A: suffix-scan global top16 hist -> prefix bin + residual target
// B: LDS histogram of low16 bits within prefix (no global ghist2)
// C: suffix-scan LDS hist -> exact 32-bit score threshold
// D: compact keys >= thr into LDS (wave-ballot aggregated)
// E: bitonic sort 1024 keys descending (full 48-bit key = exact top_k order)
// F: decode boxes + emit boxes/scores/labels + valid bitmask
__global__ void __launch_bounds__(1024) mega_select_kernel(const float* __restrict__ scores,
                                                           const int* __restrict__ classes,
                                                           const float* __restrict__ anchors,
                                                           const float* __restrict__ regression,
                                                           const uint32_t* __restrict__ ghist1,
                                                           float* __restrict__ out,
                                                           uint64_t* __restrict__ validw) {
    __shared__ uint32_t lh[32768];        // 128 KB packed pass-2 histogram
    __shared__ uint32_t ssum[1024];
    __shared__ uint64_t keys[1024];
    __shared__ uint32_t sh_prefix, sh_target, sh_thr;
    __shared__ int sh_cnt;
    const int b    = blockIdx.x;
    const int tid  = threadIdx.x;
    const int lane = tid & 63;

    #pragma unroll
    for (int t = tid; t < 32768; t += 1024) lh[t] = 0;
    keys[tid] = 0;
    if (tid == 0) sh_cnt = 0;

    // ---- Phase A
    {
        uint32_t loc[64];
        const uint4* h4 = reinterpret_cast<const uint4*>(ghist1 + (size_t)b * 65536 + tid * 64);
        #pragma unroll
        for (int k = 0; k < 16; ++k) {
            uint4 v = h4[k];
            loc[4 * k] = v.x; loc[4 * k + 1] = v.y; loc[4 * k + 2] = v.z; loc[4 * k + 3] = v.w;
        }
        uint32_t mysum = 0;
        #pragma unroll
        for (int k = 0; k < 64; ++k) mysum += loc[k];
        ssum[tid] = mysum;
        __syncthreads();
        for (int off = 1; off < 1024; off <<= 1) {
            uint32_t v = ssum[tid];
            if (tid + off < 1024) v += ssum[tid + off];
            __syncthreads();
            ssum[tid] = v;
            __syncthreads();
        }
        uint32_t acc = ssum[tid] - mysum;
        #pragma unroll
        for (int k = 63; k >= 0; --k) {
            uint32_t na = acc + loc[k];
            if (na >= (uint32_t)KSEL && acc < (uint32_t)KSEL) {
                sh_prefix = (uint32_t)(tid * 64 + k);
                sh_target = (uint32_t)KSEL - acc;
            }
            acc = na;
        }
    }
    __syncthreads();

    // ---- Phase B
    const uint32_t pfx  = sh_prefix;
    const uint32_t tgt2 = sh_target;
    const float* sc = scores + (size_t)b * A_NUM;
    for (int i = tid; i < A_NUM; i += 1024) {
        uint32_t u = mono32(sc[i]);
        if ((u >> 16) == pfx) {
            uint32_t bin = u & 0xFFFFu;
            atomicAdd(&lh[bin >> 1], (bin & 1) ? 0x10000u : 1u);
        }
    }
    __syncthreads();

    // ---- Phase C
    {
        uint32_t loc[64];
        #pragma unroll
        for (int k = 0; k < 32; ++k) {
            uint32_t w = lh[tid * 32 + k];
            loc[2 * k] = w & 0xFFFFu; loc[2 * k + 1] = w >> 16;
        }
        uint32_t mysum = 0;
        #pragma unroll
        for (int k = 0; k < 64; ++k) mysum += loc[k];
        ssum[tid] = mysum;
        __syncthreads();
        for (int off = 1; off < 1024; off <<= 1) {
            uint32_t v = ssum[tid];
            if (tid + off < 1024) v += ssum[tid + off];
            __syncthreads();
            ssum[tid] = v;
            __syncthreads();
        }
        uint32_t acc = ssum[tid] - mysum;
        #pragma unroll
        for (int k = 63; k >= 0; --k) {
            uint32_t na = acc + loc[k];
            if (na >= tgt2 && acc < tgt2) {
                sh_thr = (pfx << 16) | (uint32_t)(tid * 64 + k);
            }
            acc = na;
        }
    }
    __syncthreads();

    // ---- Phase D
    const uint32_t thr = sh_thr;
    for (int base = 0; base < A_NUM; base += 1024) {
        int i = base + tid;
        bool p = false; uint32_t u = 0;
        if (i < A_NUM) { u = mono32(sc[i]); p = (u >= thr); }
        uint64_t m = __ballot(p);
        int wb = 0;
        if (lane == 0 && m) wb = atomicAdd(&sh_cnt, __popcll(m));
        wb = __shfl(wb, 0);
        if (p) {
            int pos = wb + __popcll(m & ((1ull << lane) - 1ull));
            if (pos < 1024)
                keys[pos] = ((uint64_t)u << 16) | (uint64_t)(0xFFFFu - (uint32_t)i);
        }
    }
    __syncthreads();

    // ---- Phase E: bitonic sort descending
    for (int k = 2; k <= 1024; k <<= 1) {
        for (int j = k >> 1; j > 0; j >>= 1) {
            int partner = tid ^ j;
            if (partner > tid) {
                uint64_t a0 = keys[tid], a1 = keys[partner];
                bool up = ((tid & k) == 0);
                bool sw = up ? (a0 < a1) : (a0 > a1);
                if (sw) { keys[tid] = a1; keys[partner] = a0; }
            }
            __syncthreads();
        }
    }

    // ---- Phase F: decode + emit + validw
    float sval = -1.0f;
    if (tid < KSEL) {
        uint64_t key = keys[tid];
        int a = 0xFFFF - (int)(key & 0xFFFFu);
        size_t gi = (size_t)b * A_NUM + a;
        float s = sc[a];
        int   c = classes[gi];
        const float* an = anchors + (size_t)a * 4;
        const float* rg = regression + gi * 4;
        float y1a = an[0], x1a = an[1], y2a = an[2], x2a = an[3];
        float ya = (y1a + y2a) * 0.5f, xa = (x1a + x2a) * 0.5f;
        float ha = y2a - y1a,          wa = x2a - x1a;
        float r0 = rg[0], r1 = rg[1], r2 = rg[2], r3 = rg[3];
        float w  = expf(r3) * wa;
        float h  = expf(r2) * ha;
        float yc = r0 * ha + ya;
        float xc = r1 * wa + xa;
        float x1 = fmaxf(xc - w * 0.5f, 0.0f);
        float y1 = fmaxf(yc - h * 0.5f, 0.0f);
        float x2 = fminf(xc + w * 0.5f, IMG_F);
        float y2 = fminf(yc + h * 0.5f, IMG_F);
        int o = b * KSEL + tid;
        out[(size_t)o * 4 + 0] = x1;
        out[(size_t)o * 4 + 1] = y1;
        out[(size_t)o * 4 + 2] = x2;
        out[(size_t)o * 4 + 3] = y2;
        out[BATCH * KSEL * 4 + o]                = s;
        out[BATCH * KSEL * 4 + BATCH * KSEL + o] = (float)(c + 1);
        sval = s;
    }
    unsigned long long vm = __ballot(sval > SCORE_T);
    if ((tid & 63) == 0) validw[b * 16 + (tid >> 6)] = vm;
}

// ---- suppression bitmask matrix: sup[b][i][w] over j-word w (j>i, same class, iou>T)
__global__ void __launch_bounds__(256) supmat_kernel(const float* __restrict__ out,
                                                     uint64_t* __restrict__ supmat) {
    __shared__ float4 sbox[KSEL];
    __shared__ float  sarea[KSEL];
    __shared__ int    scls[KSEL];
    const int g    = blockIdx.x;       // 0..62 (16 i's each)
    const int b    = blockIdx.y;
    const int tid  = threadIdx.x;
    const int lane = tid & 63;
    const int wv   = tid >> 6;
    const int label_off = BATCH * KSEL * 4 + BATCH * KSEL;
    for (int j = tid; j < KSEL; j += 256) {
        float4 v = *reinterpret_cast<const float4*>(out + (size_t)(b * KSEL + j) * 4);
        sbox[j]  = v;
        sarea[j] = (v.z - v.x) * (v.w - v.y);
        scls[j]  = (int)out[label_off + b * KSEL + j];
    }
    __syncthreads();
    #pragma unroll
    for (int q = 0; q < 4; ++q) {
        int i = g * 16 + wv * 4 + q;
        if (i >= KSEL) continue;                 // wave-uniform
        float4 bi = sbox[i];
        float  ai = sarea[i];
        int    ci = scls[i];
        uint64_t* dst = supmat + ((size_t)b * 1024 + i) * 16;
        #pragma unroll
        for (int w = 0; w < 16; ++w) {
            int j = w * 64 + lane;
            bool sup = false;
            if (j > i && j < KSEL) {
                float4 bj = sbox[j];
                float lx = fmaxf(bi.x, bj.x), ly = fmaxf(bi.y, bj.y);
                float rx = fminf(bi.z, bj.z), ry = fminf(bi.w, bj.w);
                float iw = fmaxf(rx - lx, 0.0f), ih = fmaxf(ry - ly, 0.0f);
                float inter = iw * ih;
                float iou = inter / (ai + sarea[j] - inter + 1e-8f);
                sup = (iou > IOU_T) && (ci == scls[j]);
            }
            unsigned long long m = __ballot(sup);
            if (lane == 0) dst[w] = m;
        }
    }
}

// ---- serial greedy scan, one wave per image, no barriers
__global__ void __launch_bounds__(64) nms_scan_kernel(const uint64_t* __restrict__ supmat,
                                                      const uint64_t* __restrict__ validw,
                                                      float* __restrict__ out) {
    const int b    = blockIdx.x;
    const int lane = threadIdx.x;
    const int w16  = lane & 15;
    uint64_t keep = validw[b * 16 + w16];
    const uint64_t* row = supmat + (size_t)b * 1024 * 16;
    uint64_t pre[16];
    #pragma unroll
    for (int d = 0; d < 16; ++d) pre[d] = row[(size_t)d * 16 + w16];
    for (int base = 0; base < KSEL; base += 16) {
        #pragma unroll
        for (int d = 0; d < 16; ++d) {
            int i = base + d;
            uint64_t kw = __shfl(keep, i >> 6);
            if (i < KSEL && ((kw >> (i & 63)) & 1ull))
                keep &= ~pre[d];
            pre[d] = row[(size_t)(base + 16 + d) * 16 + w16];
        }
    }
    const int keep_off = BATCH * KSEL * 4 + 2 * BATCH * KSEL;
    #pragma unroll
    for (int it = 0; it < 16; ++it) {
        int j = it * 64 + lane;
        uint64_t kw = __shfl(keep, it);
        if (j < KSEL)
            out[keep_off + b * KSEL + j] = ((kw >> lane) & 1ull) ? 1.0f : 0.0f;
    }
}

extern "C" void kernel_launch(void* const* d_in, const int* in_sizes, int n_in,
                              void* d_out, int out_size, void* d_ws, size_t ws_size,
                              hipStream_t stream) {
    const float* anchors        = (const float*)d_in[1];
    const float* regression     = (const float*)d_in[2];
    const float* classification = (const float*)d_in[3];
    float* out = (float*)d_out;

    char* ws = (char*)d_ws;
    const size_t BA = (size_t)BATCH * A_NUM;          // 392832
    float*    scores   = (float*)ws;                  // 1,571,328 B
    int*      classes  = (int*)(ws + 1571328);        // 1,571,328 B -> 3,142,656
    uint64_t* validw   = (uint64_t*)(ws + 3142656);   // 1,024 B
    uint64_t* supmat   = (uint64_t*)(ws + 3145728);   // 1,048,576 B -> 4,194,304
    uint32_t* ghist1   = (uint32_t*)(ws + 4194304);   // 2,097,152 B -> 6,291,456

    int nblk = (int)((BA + 255) / 256);
    score_kernel<<<nblk, 256, 0, stream>>>(classification, scores, classes,
                                           (uint4*)ghist1);  // zeroes ghist1
    hist1_kernel<<<BATCH * HBLK, 1024, 0, stream>>>(scores, ghist1);
    mega_select_kernel<<<BATCH, 1024, 0, stream>>>(scores, classes, anchors,
                                                   regression, ghist1, out, validw);
    supmat_kernel<<<dim3(63, BATCH), 256, 0, stream>>>(out, supmat);
    nms_scan_kernel<<<BATCH, 64, 0, stream>>>(supmat, validw, out);
}

// Round 7
// 163.305 us; speedup vs baseline: 1.0979x; 1.0979x over previous
//
#include <hip/hip_runtime.h>
#include <stdint.h>

// EfficientDet post-process: score max/argmax -> top-1000 select -> rank -> NMS.
#define A_NUM   49104
#define BATCH   8
#define NCLS    90
#define KSEL    1000
#define SCORE_T 0.05f
#define IOU_T   0.5f
#define IMG_F   512.0f

#define HBLK    12          // histogram blocks per image
#define CHUNK   4092        // 12 * 4092 = 49104 exactly

// monotonic 32-bit transform: float compare == unsigned compare
__device__ __forceinline__ uint32_t mono32(float s) {
    uint32_t u = __float_as_uint(s);
    return (u & 0x80000000u) ? ~u : (u | 0x80000000u);
}

// ---- kernel 1: per-anchor class max + argmax, mask <= T to -1.
// Also zeroes both 2-MB global histograms (4 MB = 262144 uint4).
__global__ void score_kernel(const float* __restrict__ cls,
                             float* __restrict__ scores,
                             int* __restrict__ classes,
                             uint4* __restrict__ ghist_zero) {
    int i = blockIdx.x * blockDim.x + threadIdx.x;
    if (i < 262144) ghist_zero[i] = uint4{0, 0, 0, 0};
    const int BA = BATCH * A_NUM;
    if (i >= BA) return;
    const float* row = cls + (size_t)i * NCLS;
    float best = -1e30f; int bc = 0;
    #pragma unroll 9
    for (int c = 0; c < NCLS; c += 2) {
        float2 v = *reinterpret_cast<const float2*>(row + c);
        if (v.x > best) { best = v.x; bc = c; }
        if (v.y > best) { best = v.y; bc = c + 1; }
    }
    scores[i]  = (best > SCORE_T) ? best : -1.0f;
    classes[i] = bc;
}

// ---- 16-bit histogram pass (PASS=1: bits[31:16], PASS=2: bits[15:0] within prefix)
// 128 KiB LDS packed-uint16 histogram -> sparse global atomic merge.
template<int PASS>
__global__ void __launch_bounds__(1024) hist_kernel(const float* __restrict__ scores,
                                                    const uint32_t* __restrict__ prefix1,
                                                    uint32_t* __restrict__ ghist) {
    __shared__ uint32_t lh[32768];
    const int b   = blockIdx.x / HBLK;
    const int c   = blockIdx.x % HBLK;
    const int tid = threadIdx.x;
    #pragma unroll
    for (int t = tid; t < 32768; t += 1024) lh[t] = 0;
    __syncthreads();
    const float* sc = scores + (size_t)b * A_NUM;
    const uint32_t pfx = (PASS == 2) ? prefix1[b] : 0;
    const int i0 = c * CHUNK;
    const int i1 = (i0 + CHUNK < A_NUM) ? i0 + CHUNK : A_NUM;
    for (int i = i0 + tid; i < i1; i += 1024) {
        uint32_t u = mono32(sc[i]);
        uint32_t bin; bool ok;
        if (PASS == 1) { bin = u >> 16;      ok = true; }
        else           { bin = u & 0xFFFFu;  ok = ((u >> 16) == pfx); }
        if (ok) atomicAdd(&lh[bin >> 1], (bin & 1) ? 0x10000u : 1u);
    }
    __syncthreads();
    uint32_t* gh = ghist + (size_t)b * 65536;
    for (int t = tid; t < 32768; t += 1024) {
        uint32_t v = lh[t];
        if (v) {
            uint32_t lo = v & 0xFFFFu, hi = v >> 16;
            if (lo) atomicAdd(&gh[2 * t],     lo);
            if (hi) atomicAdd(&gh[2 * t + 1], hi);
        }
    }
}

// ---- boundary-bin scan over 65536 bins, 1 block/image, ONE barrier.
// Wave-level shfl suffix scan replaces the 20-barrier LDS scan.
// PASS=1: out prefix bin + residual target. PASS=2: out exact 32-bit threshold;
// also zero-init selkeys (1024 slots) and padded counters for compact.
template<int PASS>
__global__ void __launch_bounds__(1024) hscan_kernel(const uint32_t* __restrict__ ghist,
                                                     const uint32_t* __restrict__ target_in,
                                                     const uint32_t* __restrict__ prefix_in,
                                                     uint32_t* __restrict__ out0,   // bin | thr32
                                                     uint32_t* __restrict__ out1,   // target2
                                                     uint64_t* __restrict__ selkeys,
                                                     int* __restrict__ counters) {
    __shared__ uint32_t wsum[16];
    const int b    = blockIdx.x;
    const int tid  = threadIdx.x;
    const int lane = tid & 63, wid = tid >> 6;
    const uint32_t target = (PASS == 1) ? (uint32_t)KSEL : target_in[b];
    uint32_t loc[64];
    const uint4* h4 = reinterpret_cast<const uint4*>(ghist + (size_t)b * 65536 + tid * 64);
    #pragma unroll
    for (int k = 0; k < 16; ++k) {
        uint4 v = h4[k];
        loc[4 * k] = v.x; loc[4 * k + 1] = v.y; loc[4 * k + 2] = v.z; loc[4 * k + 3] = v.w;
    }
    uint32_t mysum = 0;
    #pragma unroll
    for (int k = 0; k < 64; ++k) mysum += loc[k];
    // wave suffix-inclusive scan (higher lane = higher bins)
    uint32_t v = mysum;
    #pragma unroll
    for (int off = 1; off < 64; off <<= 1) {
        uint32_t o = __shfl_down(v, off);
        if (lane + off < 64) v += o;
    }
    if (lane == 0) wsum[wid] = v;            // wave total
    __syncthreads();
    uint32_t above = 0;
    #pragma unroll
    for (int w = 0; w < 16; ++w) above += (w > wid) ? wsum[w] : 0;
    uint32_t acc = (v - mysum) + above;      // count of keys strictly above my bins
    #pragma unroll
    for (int k = 63; k >= 0; --k) {
        uint32_t na = acc + loc[k];
        if (na >= target && acc < target) {  // unique crossing
            uint32_t bin = (uint32_t)(tid * 64 + k);
            if (PASS == 1) { out0[b] = bin; out1[b] = target - acc; }
            else           { out0[b] = (prefix_in[b] << 16) | bin; }
        }
        acc = na;
    }
    if (PASS == 2) {
        selkeys[b * 1024 + tid] = 0;
        if (tid == 0) counters[b * 64] = 0;
    }
}

// ---- compact: all keys with score-bits >= thr32 (1000 + exact-score ties).
// Block-aggregated atomic (48/image) to line-padded counters: no atomic convoy.
__global__ void __launch_bounds__(1024) compact_kernel(const float* __restrict__ scores,
                                                       const uint32_t* __restrict__ thr32,
                                                       int* __restrict__ counters,
                                                       uint64_t* __restrict__ selkeys) {
    __shared__ int wbase[16];
    __shared__ int sbase;
    const int b    = blockIdx.y;
    const int tid  = threadIdx.x;
    const int i    = blockIdx.x * 1024 + tid;
    const int lane = tid & 63, wid = tid >> 6;
    bool pass = false; uint32_t u = 0;
    if (i < A_NUM) {
        u = mono32(scores[(size_t)b * A_NUM + i]);
        pass = (u >= thr32[b]);
    }
    uint64_t m = __ballot(pass);
    if (lane == 0) wbase[wid] = __popcll(m);
    __syncthreads();
    if (tid == 0) {
        int tot = 0;
        #pragma unroll
        for (int w = 0; w < 16; ++w) { int c = wbase[w]; wbase[w] = tot; tot += c; }
        sbase = tot ? atomicAdd(&counters[b * 64], tot) : 0;
    }
    __syncthreads();
    if (pass) {
        int pos = sbase + wbase[wid] + __popcll(m & ((1ull << lane) - 1ull));
        if (pos < 1024)
            selkeys[b * 1024 + pos] =
                ((uint64_t)u << 16) | (uint64_t)(0xFFFFu - (uint32_t)i);
    }
}

// ---- rank-scatter + decode + emit (replaces bitonic sort_emit).
// Keys unique -> rank = #{keys greater} is the exact descending sort position
// (identical order to jax top_k incl. index tie-break). Pads (key==0) rank
// >= #real >= 1000 -> never emitted. Grid (4, BATCH) x 256 thr, no barriers
// after the LDS load.
__global__ void __launch_bounds__(256) rank_emit_kernel(const uint64_t* __restrict__ selkeys,
                                                        const float* __restrict__ scores,
                                                        const int* __restrict__ classes,
                                                        const float* __restrict__ anchors,
                                                        const float* __restrict__ regression,
                                                        float* __restrict__ out) {
    __shared__ uint64_t k[1024];
    const int b   = blockIdx.y;
    const int tid = threadIdx.x;
    const uint64_t* sk = selkeys + b * 1024;
    for (int t = tid; t < 1024; t += 256) k[t] = sk[t];
    __syncthreads();
    const uint64_t my = k[blockIdx.x * 256 + tid];
    int rank = 0;
    #pragma unroll 8
    for (int j = 0; j < 1024; ++j) rank += (k[j] > my) ? 1 : 0;
    if (rank < KSEL && my != 0) {
        int a = 0xFFFF - (int)(my & 0xFFFFu);
        size_t gi = (size_t)b * A_NUM + a;
        float s = scores[gi];
        int   c = classes[gi];
        const float* an = anchors + (size_t)a * 4;
        const float* rg = regression + gi * 4;
        float y1a = an[0], x1a = an[1], y2a = an[2], x2a = an[3];
        float ya = (y1a + y2a) * 0.5f, xa = (x1a + x2a) * 0.5f;
        float ha = y2a - y1a,          wa = x2a - x1a;
        float r0 = rg[0], r1 = rg[1], r2 = rg[2], r3 = rg[3];
        float w  = expf(r3) * wa;
        float h  = expf(r2) * ha;
        float yc = r0 * ha + ya;
        float xc = r1 * wa + xa;
        float x1 = fmaxf(xc - w * 0.5f, 0.0f);
        float y1 = fmaxf(yc - h * 0.5f, 0.0f);
        float x2 = fminf(xc + w * 0.5f, IMG_F);
        float y2 = fminf(yc + h * 0.5f, IMG_F);
        int o = b * KSEL + rank;
        out[(size_t)o * 4 + 0] = x1;
        out[(size_t)o * 4 + 1] = y1;
        out[(size_t)o * 4 + 2] = x2;
        out[(size_t)o * 4 + 3] = y2;
        out[BATCH * KSEL * 4 + o]                = s;
        out[BATCH * KSEL * 4 + BATCH * KSEL + o] = (float)(c + 1);
    }
}

// ---- suppression bitmask matrix: sup[b][i][w] over j-word w (j>i, same class, iou>T).
// g==0 blocks additionally produce the validw bitmask from emitted scores.
__global__ void __launch_bounds__(256) supmat_kernel(const float* __restrict__ out,
                                                     uint64_t* __restrict__ supmat,
                                                     uint64_t* __restrict__ validw) {
    __shared__ float4 sbox[KSEL];
    __shared__ float  sarea[KSEL];
    __shared__ int    scls[KSEL];
    const int g    = blockIdx.x;       // 0..62 (16 i's each)
    const int b    = blockIdx.y;
    const int tid  = threadIdx.x;
    const int lane = tid & 63;
    const int wv   = tid >> 6;
    const int label_off = BATCH * KSEL * 4 + BATCH * KSEL;
    for (int j = tid; j < KSEL; j += 256) {
        float4 v = *reinterpret_cast<const float4*>(out + (size_t)(b * KSEL + j) * 4);
        sbox[j]  = v;
        sarea[j] = (v.z - v.x) * (v.w - v.y);
        scls[j]  = (int)out[label_off + b * KSEL + j];
    }
    __syncthreads();
    if (g == 0) {                      // emit valid bitmask (sorted order)
        const float* scb = out + BATCH * KSEL * 4 + b * KSEL;
        #pragma unroll
        for (int w = wv; w < 16; w += 4) {
            int j = w * 64 + lane;
            float s = (j < KSEL) ? scb[j] : -1.0f;
            unsigned long long m = __ballot(s > SCORE_T);
            if (lane == 0) validw[b * 16 + w] = m;
        }
    }
    #pragma unroll
    for (int q = 0; q < 4; ++q) {
        int i = g * 16 + wv * 4 + q;
        if (i >= KSEL) continue;                 // wave-uniform
        float4 bi = sbox[i];
        float  ai = sarea[i];
        int    ci = scls[i];
        uint64_t* dst = supmat + ((size_t)b * 1024 + i) * 16;
        #pragma unroll
        for (int w = 0; w < 16; ++w) {
            int j = w * 64 + lane;
            bool sup = false;
            if (j > i && j < KSEL) {
                float4 bj = sbox[j];
                float lx = fmaxf(bi.x, bj.x), ly = fmaxf(bi.y, bj.y);
                float rx = fminf(bi.z, bj.z), ry = fminf(bi.w, bj.w);
                float iw = fmaxf(rx - lx, 0.0f), ih = fmaxf(ry - ly, 0.0f);
                float inter = iw * ih;
                float iou = inter / (ai + sarea[j] - inter + 1e-8f);
                sup = (iou > IOU_T) && (ci == scls[j]);
            }
            unsigned long long m = __ballot(sup);
            if (lane == 0) dst[w] = m;
        }
    }
}

// ---- serial greedy scan, one wave per image, no barriers
__global__ void __launch_bounds__(64) nms_scan_kernel(const uint64_t* __restrict__ supmat,
                                                      const uint64_t* __restrict__ validw,
                                                      float* __restrict__ out) {
    const int b    = blockIdx.x;
    const int lane = threadIdx.x;
    const int w16  = lane & 15;
    uint64_t keep = validw[b * 16 + w16];
    const uint64_t* row = supmat + (size_t)b * 1024 * 16;
    uint64_t pre[16];
    #pragma unroll
    for (int d = 0; d < 16; ++d) pre[d] = row[(size_t)d * 16 + w16];
    for (int base = 0; base < KSEL; base += 16) {
        #pragma unroll
        for (int d = 0; d < 16; ++d) {
            int i = base + d;
            uint64_t kw = __shfl(keep, i >> 6);
            if (i < KSEL && ((kw >> (i & 63)) & 1ull))
                keep &= ~pre[d];
            pre[d] = row[(size_t)(base + 16 + d) * 16 + w16];
        }
    }
    const int keep_off = BATCH * KSEL * 4 + 2 * BATCH * KSEL;
    #pragma unroll
    for (int it = 0; it < 16; ++it) {
        int j = it * 64 + lane;
        uint64_t kw = __shfl(keep, it);
        if (j < KSEL)
            out[keep_off + b * KSEL + j] = ((kw >> lane) & 1ull) ? 1.0f : 0.0f;
    }
}

extern "C" void kernel_launch(void* const* d_in, const int* in_sizes, int n_in,
                              void* d_out, int out_size, void* d_ws, size_t ws_size,
                              hipStream_t stream) {
    const float* anchors        = (const float*)d_in[1];
    const float* regression     = (const float*)d_in[2];
    const float* classification = (const float*)d_in[3];
    float* out = (float*)d_out;

    char* ws = (char*)d_ws;
    const size_t BA = (size_t)BATCH * A_NUM;          // 392832
    float*    scores   = (float*)ws;                  // 1,571,328 B
    int*      classes  = (int*)(ws + 1571328);        // 1,571,328 B -> 3,142,656
    uint64_t* selkeys  = (uint64_t*)(ws + 3142656);   // 65,536 B   -> 3,208,192
    uint32_t* prefix1  = (uint32_t*)(ws + 3208192);   // 256 B
    uint32_t* target2  = (uint32_t*)(ws + 3208448);   // 256 B
    uint32_t* thr32    = (uint32_t*)(ws + 3208704);   // 256 B
    int*      counters = (int*)(ws + 3208960);        // 2,048 B (8 x 256B lines)
    uint64_t* validw   = (uint64_t*)(ws + 3211008);   // 1,024 B  -> 3,212,032
    uint64_t* supmat   = (uint64_t*)(ws + 3212032);   // 1,048,576 B -> 4,260,608
    uint32_t* ghist1   = (uint32_t*)(ws + 4260608);   // 2,097,152 B -> 6,357,760
    uint32_t* ghist2   = (uint32_t*)(ws + 6357760);   // 2,097,152 B -> 8,454,912

    int nblk = (int)((BA + 255) / 256);
    score_kernel<<<nblk, 256, 0, stream>>>(classification, scores, classes,
                                           (uint4*)ghist1);  // zeroes ghist1+ghist2
    hist_kernel<1><<<BATCH * HBLK, 1024, 0, stream>>>(scores, nullptr, ghist1);
    hscan_kernel<1><<<BATCH, 1024, 0, stream>>>(ghist1, nullptr, nullptr,
                                                prefix1, target2, nullptr, nullptr);
    hist_kernel<2><<<BATCH * HBLK, 1024, 0, stream>>>(scores, prefix1, ghist2);
    hscan_kernel<2><<<BATCH, 1024, 0, stream>>>(ghist2, target2, prefix1,
                                                thr32, nullptr, selkeys, counters);
    compact_kernel<<<dim3(48, BATCH), 1024, 0, stream>>>(scores, thr32, counters, selkeys);
    rank_emit_kernel<<<dim3(4, BATCH), 256, 0, stream>>>(selkeys, scores, classes,
                                                         anchors, regression, out);
    supmat_kernel<<<dim3(63, BATCH), 256, 0, stream>>>(out, supmat, validw);
    nms_scan_kernel<<<BATCH, 64, 0, stream>>>(supmat, validw, out);
}

// Round 8
// 113.365 us; speedup vs baseline: 1.5815x; 1.4405x over previous
//
#include <hip/hip_runtime.h>
#include <stdint.h>

// EfficientDet post-process: score max/argmax -> top-1000 select -> rank -> NMS.
#define A_NUM   49104
#define BATCH   8
#define NCLS    90
#define KSEL    1000
#define SCORE_T 0.05f
#define IOU_T   0.5f
#define IMG_F   512.0f

#define HBLK    12          // histogram blocks per image
#define CHUNK   4092        // 12 * 4092 = 49104 exactly

// monotonic 32-bit transform: float compare == unsigned compare
__device__ __forceinline__ uint32_t mono32(float s) {
    uint32_t u = __float_as_uint(s);
    return (u & 0x80000000u) ? ~u : (u | 0x80000000u);
}

// ---- kernel 1: per-anchor class max + argmax, mask <= T to -1.
// Also zeroes both 2-MB global histograms (4 MB = 262144 uint4).
__global__ void score_kernel(const float* __restrict__ cls,
                             float* __restrict__ scores,
                             int* __restrict__ classes,
                             uint4* __restrict__ ghist_zero) {
    int i = blockIdx.x * blockDim.x + threadIdx.x;
    if (i < 262144) ghist_zero[i] = uint4{0, 0, 0, 0};
    const int BA = BATCH * A_NUM;
    if (i >= BA) return;
    const float* row = cls + (size_t)i * NCLS;
    float best = -1e30f; int bc = 0;
    #pragma unroll 9
    for (int c = 0; c < NCLS; c += 2) {
        float2 v = *reinterpret_cast<const float2*>(row + c);
        if (v.x > best) { best = v.x; bc = c; }
        if (v.y > best) { best = v.y; bc = c + 1; }
    }
    scores[i]  = (best > SCORE_T) ? best : -1.0f;
    classes[i] = bc;
}

// ---- 16-bit histogram pass (PASS=1: bits[31:16], PASS=2: bits[15:0] within prefix)
// 128 KiB LDS packed-uint16 histogram -> sparse global atomic merge.
template<int PASS>
__global__ void __launch_bounds__(1024) hist_kernel(const float* __restrict__ scores,
                                                    const uint32_t* __restrict__ prefix1,
                                                    uint32_t* __restrict__ ghist) {
    __shared__ uint32_t lh[32768];
    const int b   = blockIdx.x / HBLK;
    const int c   = blockIdx.x % HBLK;
    const int tid = threadIdx.x;
    #pragma unroll
    for (int t = tid; t < 32768; t += 1024) lh[t] = 0;
    __syncthreads();
    const float* sc = scores + (size_t)b * A_NUM;
    const uint32_t pfx = (PASS == 2) ? prefix1[b] : 0;
    const int i0 = c * CHUNK;
    const int i1 = (i0 + CHUNK < A_NUM) ? i0 + CHUNK : A_NUM;
    for (int i = i0 + tid; i < i1; i += 1024) {
        uint32_t u = mono32(sc[i]);
        uint32_t bin; bool ok;
        if (PASS == 1) { bin = u >> 16;      ok = true; }
        else           { bin = u & 0xFFFFu;  ok = ((u >> 16) == pfx); }
        if (ok) atomicAdd(&lh[bin >> 1], (bin & 1) ? 0x10000u : 1u);
    }
    __syncthreads();
    uint32_t* gh = ghist + (size_t)b * 65536;
    for (int t = tid; t < 32768; t += 1024) {
        uint32_t v = lh[t];
        if (v) {
            uint32_t lo = v & 0xFFFFu, hi = v >> 16;
            if (lo) atomicAdd(&gh[2 * t],     lo);
            if (hi) atomicAdd(&gh[2 * t + 1], hi);
        }
    }
}

// ---- boundary-bin scan over 65536 bins, 1 block/image, ONE barrier.
template<int PASS>
__global__ void __launch_bounds__(1024) hscan_kernel(const uint32_t* __restrict__ ghist,
                                                     const uint32_t* __restrict__ target_in,
                                                     const uint32_t* __restrict__ prefix_in,
                                                     uint32_t* __restrict__ out0,   // bin | thr32
                                                     uint32_t* __restrict__ out1,   // target2
                                                     uint64_t* __restrict__ selkeys,
                                                     int* __restrict__ counters) {
    __shared__ uint32_t wsum[16];
    const int b    = blockIdx.x;
    const int tid  = threadIdx.x;
    const int lane = tid & 63, wid = tid >> 6;
    const uint32_t target = (PASS == 1) ? (uint32_t)KSEL : target_in[b];
    uint32_t loc[64];
    const uint4* h4 = reinterpret_cast<const uint4*>(ghist + (size_t)b * 65536 + tid * 64);
    #pragma unroll
    for (int k = 0; k < 16; ++k) {
        uint4 v = h4[k];
        loc[4 * k] = v.x; loc[4 * k + 1] = v.y; loc[4 * k + 2] = v.z; loc[4 * k + 3] = v.w;
    }
    uint32_t mysum = 0;
    #pragma unroll
    for (int k = 0; k < 64; ++k) mysum += loc[k];
    uint32_t v = mysum;
    #pragma unroll
    for (int off = 1; off < 64; off <<= 1) {
        uint32_t o = __shfl_down(v, off);
        if (lane + off < 64) v += o;
    }
    if (lane == 0) wsum[wid] = v;            // wave total
    __syncthreads();
    uint32_t above = 0;
    #pragma unroll
    for (int w = 0; w < 16; ++w) above += (w > wid) ? wsum[w] : 0;
    uint32_t acc = (v - mysum) + above;      // count of keys strictly above my bins
    #pragma unroll
    for (int k = 63; k >= 0; --k) {
        uint32_t na = acc + loc[k];
        if (na >= target && acc < target) {  // unique crossing
            uint32_t bin = (uint32_t)(tid * 64 + k);
            if (PASS == 1) { out0[b] = bin; out1[b] = target - acc; }
            else           { out0[b] = (prefix_in[b] << 16) | bin; }
        }
        acc = na;
    }
    if (PASS == 2) {
        selkeys[b * 1024 + tid] = 0;
        if (tid == 0) counters[b * 64] = 0;
    }
}

// ---- compact: all keys with score-bits >= thr32 (1000 + exact-score ties).
__global__ void __launch_bounds__(1024) compact_kernel(const float* __restrict__ scores,
                                                       const uint32_t* __restrict__ thr32,
                                                       int* __restrict__ counters,
                                                       uint64_t* __restrict__ selkeys) {
    __shared__ int wbase[16];
    __shared__ int sbase;
    const int b    = blockIdx.y;
    const int tid  = threadIdx.x;
    const int i    = blockIdx.x * 1024 + tid;
    const int lane = tid & 63, wid = tid >> 6;
    bool pass = false; uint32_t u = 0;
    if (i < A_NUM) {
        u = mono32(scores[(size_t)b * A_NUM + i]);
        pass = (u >= thr32[b]);
    }
    uint64_t m = __ballot(pass);
    if (lane == 0) wbase[wid] = __popcll(m);
    __syncthreads();
    if (tid == 0) {
        int tot = 0;
        #pragma unroll
        for (int w = 0; w < 16; ++w) { int c = wbase[w]; wbase[w] = tot; tot += c; }
        sbase = tot ? atomicAdd(&counters[b * 64], tot) : 0;
    }
    __syncthreads();
    if (pass) {
        int pos = sbase + wbase[wid] + __popcll(m & ((1ull << lane) - 1ull));
        if (pos < 1024)
            selkeys[b * 1024 + pos] =
                ((uint64_t)u << 16) | (uint64_t)(0xFFFFu - (uint32_t)i);
    }
}

// ---- rank-scatter + decode + emit. Keys unique -> rank = #{keys greater}.
__global__ void __launch_bounds__(256) rank_emit_kernel(const uint64_t* __restrict__ selkeys,
                                                        const float* __restrict__ scores,
                                                        const int* __restrict__ classes,
                                                        const float* __restrict__ anchors,
                                                        const float* __restrict__ regression,
                                                        float* __restrict__ out) {
    __shared__ uint64_t k[1024];
    const int b   = blockIdx.y;
    const int tid = threadIdx.x;
    const uint64_t* sk = selkeys + b * 1024;
    for (int t = tid; t < 1024; t += 256) k[t] = sk[t];
    __syncthreads();
    const uint64_t my = k[blockIdx.x * 256 + tid];
    int rank = 0;
    #pragma unroll 8
    for (int j = 0; j < 1024; ++j) rank += (k[j] > my) ? 1 : 0;
    if (rank < KSEL && my != 0) {
        int a = 0xFFFF - (int)(my & 0xFFFFu);
        size_t gi = (size_t)b * A_NUM + a;
        float s = scores[gi];
        int   c = classes[gi];
        const float* an = anchors + (size_t)a * 4;
        const float* rg = regression + gi * 4;
        float y1a = an[0], x1a = an[1], y2a = an[2], x2a = an[3];
        float ya = (y1a + y2a) * 0.5f, xa = (x1a + x2a) * 0.5f;
        float ha = y2a - y1a,          wa = x2a - x1a;
        float r0 = rg[0], r1 = rg[1], r2 = rg[2], r3 = rg[3];
        float w  = expf(r3) * wa;
        float h  = expf(r2) * ha;
        float yc = r0 * ha + ya;
        float xc = r1 * wa + xa;
        float x1 = fmaxf(xc - w * 0.5f, 0.0f);
        float y1 = fmaxf(yc - h * 0.5f, 0.0f);
        float x2 = fminf(xc + w * 0.5f, IMG_F);
        float y2 = fminf(yc + h * 0.5f, IMG_F);
        int o = b * KSEL + rank;
        out[(size_t)o * 4 + 0] = x1;
        out[(size_t)o * 4 + 1] = y1;
        out[(size_t)o * 4 + 2] = x2;
        out[(size_t)o * 4 + 3] = y2;
        out[BATCH * KSEL * 4 + o]                = s;
        out[BATCH * KSEL * 4 + BATCH * KSEL + o] = (float)(c + 1);
    }
}

// ---- suppression bitmask matrix, SPARSE output: writes sup word only if
// nonzero, plus a per-row 16-bit nonzero-word mask. g==0 also emits validw.
__global__ void __launch_bounds__(256) supmat_kernel(const float* __restrict__ out,
                                                     uint64_t* __restrict__ supmat,
                                                     uint16_t* __restrict__ rowmask,
                                                     uint64_t* __restrict__ validw) {
    __shared__ float4 sbox[KSEL];
    __shared__ float  sarea[KSEL];
    __shared__ int    scls[KSEL];
    const int g    = blockIdx.x;       // 0..62 (16 i's each)
    const int b    = blockIdx.y;
    const int tid  = threadIdx.x;
    const int lane = tid & 63;
    const int wv   = tid >> 6;
    const int label_off = BATCH * KSEL * 4 + BATCH * KSEL;
    for (int j = tid; j < KSEL; j += 256) {
        float4 v = *reinterpret_cast<const float4*>(out + (size_t)(b * KSEL + j) * 4);
        sbox[j]  = v;
        sarea[j] = (v.z - v.x) * (v.w - v.y);
        scls[j]  = (int)out[label_off + b * KSEL + j];
    }
    __syncthreads();
    if (g == 0) {                      // emit valid bitmask (sorted order)
        const float* scb = out + BATCH * KSEL * 4 + b * KSEL;
        #pragma unroll
        for (int w = wv; w < 16; w += 4) {
            int j = w * 64 + lane;
            float s = (j < KSEL) ? scb[j] : -1.0f;
            unsigned long long m = __ballot(s > SCORE_T);
            if (lane == 0) validw[b * 16 + w] = m;
        }
    }
    #pragma unroll
    for (int q = 0; q < 4; ++q) {
        int i = g * 16 + wv * 4 + q;
        if (i >= KSEL) continue;                 // wave-uniform
        float4 bi = sbox[i];
        float  ai = sarea[i];
        int    ci = scls[i];
        uint64_t* dst = supmat + ((size_t)b * 1024 + i) * 16;
        uint32_t nzm = 0;
        #pragma unroll
        for (int w = 0; w < 16; ++w) {
            int j = w * 64 + lane;
            bool sup = false;
            if (j > i && j < KSEL) {
                float4 bj = sbox[j];
                float lx = fmaxf(bi.x, bj.x), ly = fmaxf(bi.y, bj.y);
                float rx = fminf(bi.z, bj.z), ry = fminf(bi.w, bj.w);
                float iw = fmaxf(rx - lx, 0.0f), ih = fmaxf(ry - ly, 0.0f);
                float inter = iw * ih;
                float iou = inter / (ai + sarea[j] - inter + 1e-8f);
                sup = (iou > IOU_T) && (ci == scls[j]);
            }
            unsigned long long m = __ballot(sup);
            if (m) {
                nzm |= 1u << w;
                if (lane == 0) dst[w] = m;
            }
        }
        if (lane == 0) rowmask[(size_t)b * 1024 + i] = (uint16_t)nzm;
    }
}

// ---- sparse greedy scan: one block/image. Build 1024-bit "has suppressors"
// bitmap; a single lane walks only set bits of keep&nz (typically none),
// applying the few real suppression rows. Keep state in LDS. No shfl chain.
__global__ void __launch_bounds__(64) nms_scan_kernel(const uint64_t* __restrict__ supmat,
                                                      const uint16_t* __restrict__ rowmask,
                                                      const uint64_t* __restrict__ validw,
                                                      float* __restrict__ out) {
    __shared__ uint64_t kp[16];
    __shared__ uint64_t nzs[16];
    __shared__ uint16_t rm_lds[1024];
    const int b    = blockIdx.x;
    const int lane = threadIdx.x;
    if (lane < 16) kp[lane] = validw[b * 16 + lane];
    // stage rowmask (2 KB) coalesced
    const uint32_t* rm32 = reinterpret_cast<const uint32_t*>(rowmask + (size_t)b * 1024);
    #pragma unroll
    for (int t = lane; t < 512; t += 64) ((uint32_t*)rm_lds)[t] = rm32[t];
    __syncthreads();
    #pragma unroll
    for (int it = 0; it < 16; ++it) {
        int i = it * 64 + lane;
        unsigned long long m = __ballot(rm_lds[i] != 0);
        if (lane == 0) nzs[it] = m;
    }
    __syncthreads();
    if (lane == 0) {
        const uint64_t* rowbase = supmat + (size_t)b * 1024 * 16;
        #pragma unroll 1
        for (int w16 = 0; w16 < 16; ++w16) {
            uint64_t kw   = kp[w16];
            uint64_t nzw  = nzs[w16];
            uint64_t done = 0;
            for (;;) {
                uint64_t cand = kw & nzw & ~done;
                if (!cand) break;
                int bit = __ffsll((unsigned long long)cand) - 1;
                done |= 1ull << bit;
                int i = w16 * 64 + bit;
                uint32_t m = rm_lds[i];
                const uint64_t* r = rowbase + (size_t)i * 16;
                while (m) {
                    int w = __ffs(m) - 1; m &= m - 1;   // w >= w16 (rows have j>i only)
                    uint64_t rv = r[w];
                    uint64_t nk = kp[w] & ~rv;
                    kp[w] = nk;
                    if (w == w16) kw = nk;
                }
            }
        }
    }
    __syncthreads();
    const int keep_off = BATCH * KSEL * 4 + 2 * BATCH * KSEL;
    #pragma unroll
    for (int it = 0; it < 16; ++it) {
        uint64_t kw = kp[it];                    // LDS broadcast
        int j = it * 64 + lane;
        if (j < KSEL)
            out[keep_off + b * KSEL + j] = ((kw >> lane) & 1ull) ? 1.0f : 0.0f;
    }
}

extern "C" void kernel_launch(void* const* d_in, const int* in_sizes, int n_in,
                              void* d_out, int out_size, void* d_ws, size_t ws_size,
                              hipStream_t stream) {
    const float* anchors        = (const float*)d_in[1];
    const float* regression     = (const float*)d_in[2];
    const float* classification = (const float*)d_in[3];
    float* out = (float*)d_out;

    char* ws = (char*)d_ws;
    const size_t BA = (size_t)BATCH * A_NUM;          // 392832
    float*    scores   = (float*)ws;                  // 1,571,328 B
    int*      classes  = (int*)(ws + 1571328);        // 1,571,328 B -> 3,142,656
    uint64_t* selkeys  = (uint64_t*)(ws + 3142656);   // 65,536 B   -> 3,208,192
    uint32_t* prefix1  = (uint32_t*)(ws + 3208192);   // 256 B
    uint32_t* target2  = (uint32_t*)(ws + 3208448);   // 256 B
    uint32_t* thr32    = (uint32_t*)(ws + 3208704);   // 256 B
    int*      counters = (int*)(ws + 3208960);        // 2,048 B (8 x 256B lines)
    uint64_t* validw   = (uint64_t*)(ws + 3211008);   // 1,024 B  -> 3,212,032
    uint64_t* supmat   = (uint64_t*)(ws + 3212032);   // 1,048,576 B -> 4,260,608
    uint32_t* ghist1   = (uint32_t*)(ws + 4260608);   // 2,097,152 B -> 6,357,760
    uint32_t* ghist2   = (uint32_t*)(ws + 6357760);   // 2,097,152 B -> 8,454,912
    uint16_t* rowmask  = (uint16_t*)(ws + 8454912);   // 16,384 B   -> 8,471,296

    int nblk = (int)((BA + 255) / 256);
    score_kernel<<<nblk, 256, 0, stream>>>(classification, scores, classes,
                                           (uint4*)ghist1);  // zeroes ghist1+ghist2
    hist_kernel<1><<<BATCH * HBLK, 1024, 0, stream>>>(scores, nullptr, ghist1);
    hscan_kernel<1><<<BATCH, 1024, 0, stream>>>(ghist1, nullptr, nullptr,
                                                prefix1, target2, nullptr, nullptr);
    hist_kernel<2><<<BATCH * HBLK, 1024, 0, stream>>>(scores, prefix1, ghist2);
    hscan_kernel<2><<<BATCH, 1024, 0, stream>>>(ghist2, target2, prefix1,
                                                thr32, nullptr, selkeys, counters);
    compact_kernel<<<dim3(48, BATCH), 1024, 0, stream>>>(scores, thr32, counters, selkeys);
    rank_emit_kernel<<<dim3(4, BATCH), 256, 0, stream>>>(selkeys, scores, classes,
                                                         anchors, regression, out);
    supmat_kernel<<<dim3(63, BATCH), 256, 0, stream>>>(out, supmat, rowmask, validw);
    nms_scan_kernel<<<BATCH, 64, 0, stream>>>(supmat, rowmask, validw, out);
}

// Round 9
// 109.697 us; speedup vs baseline: 1.6344x; 1.0334x over previous
//
#include <hip/hip_runtime.h>
#include <stdint.h>

// EfficientDet post-process: score max/argmax -> top-1000 select -> rank -> NMS.
#define A_NUM   49104
#define BATCH   8
#define NCLS    90
#define KSEL    1000
#define SCORE_T 0.05f
#define IOU_T   0.5f
#define IMG_F   512.0f

#define HBLK    12          // histogram blocks per image
#define CHUNK   4092        // 12 * 4092 = 49104 exactly
#define SROWS   128         // rows per score block (392832 = 3069 * 128 exactly)

// monotonic 32-bit transform: float compare == unsigned compare
__device__ __forceinline__ uint32_t mono32(float s) {
    uint32_t u = __float_as_uint(s);
    return (u & 0x80000000u) ? ~u : (u | 0x80000000u);
}

// ---- kernel 1: per-anchor class max + argmax, mask <= T to -1.
// LDS-staged: coalesced float2 global loads into a stride-94-padded tile
// (2-way LDS conflicts only), then 2 threads/row reduce. Halves overlap at
// cols 44/45; combine rule (m_hi > m_lo strict) keeps first-max semantics.
// Also zeroes both 2-MB global histograms (4 MB = 262144 uint4).
__global__ void __launch_bounds__(256) score_kernel(const float* __restrict__ cls,
                                                    float* __restrict__ scores,
                                                    int* __restrict__ classes,
                                                    uint4* __restrict__ ghist_zero) {
    __shared__ float tile[SROWS * 94];
    const int tid = threadIdx.x;
    const int gzi = blockIdx.x * 256 + tid;
    if (gzi < 262144) ghist_zero[gzi] = uint4{0, 0, 0, 0};
    const size_t row0 = (size_t)blockIdx.x * SROWS;
    // stage 128 rows x 90 floats = 5760 float2, perfectly coalesced
    const float2* src = reinterpret_cast<const float2*>(cls + row0 * NCLS);
    #pragma unroll
    for (int it = 0; it < 23; ++it) {
        int t = it * 256 + tid;
        if (t < SROWS * 45) {
            float2 v = src[t];
            int r  = t / 45;
            int c2 = t - r * 45;
            *reinterpret_cast<float2*>(&tile[r * 94 + 2 * c2]) = v;
        }
    }
    __syncthreads();
    const int r    = tid >> 1;
    const int half = tid & 1;
    const float* rowp = &tile[r * 94];
    float best = -1e30f; int bc = 0;
    const int c0 = half * 44;               // half0: 0..45, half1: 44..89
    #pragma unroll
    for (int k = 0; k < 23; ++k) {
        int c = c0 + 2 * k;
        float2 v = *reinterpret_cast<const float2*>(&rowp[c]);
        if (v.x > best) { best = v.x; bc = c; }
        if (v.y > best) { best = v.y; bc = c + 1; }
    }
    float mo = __shfl_xor(best, 1);
    int   io = __shfl_xor(bc, 1);
    float m_lo = half ? mo : best;  int i_lo = half ? io : bc;
    float m_hi = half ? best : mo;  int i_hi = half ? bc : io;
    float m = (m_hi > m_lo) ? m_hi : m_lo;
    int   ic = (m_hi > m_lo) ? i_hi : i_lo;
    if (!half) {
        size_t gi = row0 + r;
        scores[gi]  = (m > SCORE_T) ? m : -1.0f;
        classes[gi] = ic;
    }
}

// ---- 16-bit histogram pass (PASS=1: bits[31:16], PASS=2: bits[15:0] within prefix)
// 128 KiB LDS packed-uint16 histogram -> sparse global atomic merge.
template<int PASS>
__global__ void __launch_bounds__(1024) hist_kernel(const float* __restrict__ scores,
                                                    const uint32_t* __restrict__ prefix1,
                                                    uint32_t* __restrict__ ghist) {
    __shared__ uint32_t lh[32768];
    const int b   = blockIdx.x / HBLK;
    const int c   = blockIdx.x % HBLK;
    const int tid = threadIdx.x;
    #pragma unroll
    for (int t = tid; t < 32768; t += 1024) lh[t] = 0;
    __syncthreads();
    const float* sc = scores + (size_t)b * A_NUM;
    const uint32_t pfx = (PASS == 2) ? prefix1[b] : 0;
    const int i0 = c * CHUNK;
    const int i1 = (i0 + CHUNK < A_NUM) ? i0 + CHUNK : A_NUM;
    for (int i = i0 + tid; i < i1; i += 1024) {
        uint32_t u = mono32(sc[i]);
        uint32_t bin; bool ok;
        if (PASS == 1) { bin = u >> 16;      ok = true; }
        else           { bin = u & 0xFFFFu;  ok = ((u >> 16) == pfx); }
        if (ok) atomicAdd(&lh[bin >> 1], (bin & 1) ? 0x10000u : 1u);
    }
    __syncthreads();
    uint32_t* gh = ghist + (size_t)b * 65536;
    for (int t = tid; t < 32768; t += 1024) {
        uint32_t v = lh[t];
        if (v) {
            uint32_t lo = v & 0xFFFFu, hi = v >> 16;
            if (lo) atomicAdd(&gh[2 * t],     lo);
            if (hi) atomicAdd(&gh[2 * t + 1], hi);
        }
    }
}

// ---- boundary-bin scan over 65536 bins, 1 block/image, ONE barrier.
template<int PASS>
__global__ void __launch_bounds__(1024) hscan_kernel(const uint32_t* __restrict__ ghist,
                                                     const uint32_t* __restrict__ target_in,
                                                     const uint32_t* __restrict__ prefix_in,
                                                     uint32_t* __restrict__ out0,   // bin | thr32
                                                     uint32_t* __restrict__ out1,   // target2
                                                     uint64_t* __restrict__ selkeys,
                                                     int* __restrict__ counters) {
    __shared__ uint32_t wsum[16];
    const int b    = blockIdx.x;
    const int tid  = threadIdx.x;
    const int lane = tid & 63, wid = tid >> 6;
    const uint32_t target = (PASS == 1) ? (uint32_t)KSEL : target_in[b];
    uint32_t loc[64];
    const uint4* h4 = reinterpret_cast<const uint4*>(ghist + (size_t)b * 65536 + tid * 64);
    #pragma unroll
    for (int k = 0; k < 16; ++k) {
        uint4 v = h4[k];
        loc[4 * k] = v.x; loc[4 * k + 1] = v.y; loc[4 * k + 2] = v.z; loc[4 * k + 3] = v.w;
    }
    uint32_t mysum = 0;
    #pragma unroll
    for (int k = 0; k < 64; ++k) mysum += loc[k];
    uint32_t v = mysum;
    #pragma unroll
    for (int off = 1; off < 64; off <<= 1) {
        uint32_t o = __shfl_down(v, off);
        if (lane + off < 64) v += o;
    }
    if (lane == 0) wsum[wid] = v;            // wave total
    __syncthreads();
    uint32_t above = 0;
    #pragma unroll
    for (int w = 0; w < 16; ++w) above += (w > wid) ? wsum[w] : 0;
    uint32_t acc = (v - mysum) + above;      // count of keys strictly above my bins
    #pragma unroll
    for (int k = 63; k >= 0; --k) {
        uint32_t na = acc + loc[k];
        if (na >= target && acc < target) {  // unique crossing
            uint32_t bin = (uint32_t)(tid * 64 + k);
            if (PASS == 1) { out0[b] = bin; out1[b] = target - acc; }
            else           { out0[b] = (prefix_in[b] << 16) | bin; }
        }
        acc = na;
    }
    if (PASS == 2) {
        selkeys[b * 1024 + tid] = 0;
        if (tid == 0) counters[b * 64] = 0;
    }
}

// ---- compact: all keys with score-bits >= thr32 (1000 + exact-score ties).
__global__ void __launch_bounds__(1024) compact_kernel(const float* __restrict__ scores,
                                                       const uint32_t* __restrict__ thr32,
                                                       int* __restrict__ counters,
                                                       uint64_t* __restrict__ selkeys) {
    __shared__ int wbase[16];
    __shared__ int sbase;
    const int b    = blockIdx.y;
    const int tid  = threadIdx.x;
    const int i    = blockIdx.x * 1024 + tid;
    const int lane = tid & 63, wid = tid >> 6;
    bool pass = false; uint32_t u = 0;
    if (i < A_NUM) {
        u = mono32(scores[(size_t)b * A_NUM + i]);
        pass = (u >= thr32[b]);
    }
    uint64_t m = __ballot(pass);
    if (lane == 0) wbase[wid] = __popcll(m);
    __syncthreads();
    if (tid == 0) {
        int tot = 0;
        #pragma unroll
        for (int w = 0; w < 16; ++w) { int c = wbase[w]; wbase[w] = tot; tot += c; }
        sbase = tot ? atomicAdd(&counters[b * 64], tot) : 0;
    }
    __syncthreads();
    if (pass) {
        int pos = sbase + wbase[wid] + __popcll(m & ((1ull << lane) - 1ull));
        if (pos < 1024)
            selkeys[b * 1024 + pos] =
                ((uint64_t)u << 16) | (uint64_t)(0xFFFFu - (uint32_t)i);
    }
}

// ---- rank-scatter + decode + emit. Keys unique -> rank = #{keys greater}.
__global__ void __launch_bounds__(256) rank_emit_kernel(const uint64_t* __restrict__ selkeys,
                                                        const float* __restrict__ scores,
                                                        const int* __restrict__ classes,
                                                        const float* __restrict__ anchors,
                                                        const float* __restrict__ regression,
                                                        float* __restrict__ out) {
    __shared__ uint64_t k[1024];
    const int b   = blockIdx.y;
    const int tid = threadIdx.x;
    const uint64_t* sk = selkeys + b * 1024;
    for (int t = tid; t < 1024; t += 256) k[t] = sk[t];
    __syncthreads();
    const uint64_t my = k[blockIdx.x * 256 + tid];
    int rank = 0;
    #pragma unroll 8
    for (int j = 0; j < 1024; ++j) rank += (k[j] > my) ? 1 : 0;
    if (rank < KSEL && my != 0) {
        int a = 0xFFFF - (int)(my & 0xFFFFu);
        size_t gi = (size_t)b * A_NUM + a;
        float s = scores[gi];
        int   c = classes[gi];
        const float* an = anchors + (size_t)a * 4;
        const float* rg = regression + gi * 4;
        float y1a = an[0], x1a = an[1], y2a = an[2], x2a = an[3];
        float ya = (y1a + y2a) * 0.5f, xa = (x1a + x2a) * 0.5f;
        float ha = y2a - y1a,          wa = x2a - x1a;
        float r0 = rg[0], r1 = rg[1], r2 = rg[2], r3 = rg[3];
        float w  = expf(r3) * wa;
        float h  = expf(r2) * ha;
        float yc = r0 * ha + ya;
        float xc = r1 * wa + xa;
        float x1 = fmaxf(xc - w * 0.5f, 0.0f);
        float y1 = fmaxf(yc - h * 0.5f, 0.0f);
        float x2 = fminf(xc + w * 0.5f, IMG_F);
        float y2 = fminf(yc + h * 0.5f, IMG_F);
        int o = b * KSEL + rank;
        out[(size_t)o * 4 + 0] = x1;
        out[(size_t)o * 4 + 1] = y1;
        out[(size_t)o * 4 + 2] = x2;
        out[(size_t)o * 4 + 3] = y2;
        out[BATCH * KSEL * 4 + o]                = s;
        out[BATCH * KSEL * 4 + BATCH * KSEL + o] = (float)(c + 1);
    }
}

// ---- suppression bitmask matrix, SPARSE output: writes sup word only if
// nonzero, plus a per-row 16-bit nonzero-word mask. g==0 also emits validw.
__global__ void __launch_bounds__(256) supmat_kernel(const float* __restrict__ out,
                                                     uint64_t* __restrict__ supmat,
                                                     uint16_t* __restrict__ rowmask,
                                                     uint64_t* __restrict__ validw) {
    __shared__ float4 sbox[KSEL];
    __shared__ float  sarea[KSEL];
    __shared__ int    scls[KSEL];
    const int g    = blockIdx.x;       // 0..62 (16 i's each)
    const int b    = blockIdx.y;
    const int tid  = threadIdx.x;
    const int lane = tid & 63;
    const int wv   = tid >> 6;
    const int label_off = BATCH * KSEL * 4 + BATCH * KSEL;
    for (int j = tid; j < KSEL; j += 256) {
        float4 v = *reinterpret_cast<const float4*>(out + (size_t)(b * KSEL + j) * 4);
        sbox[j]  = v;
        sarea[j] = (v.z - v.x) * (v.w - v.y);
        scls[j]  = (int)out[label_off + b * KSEL + j];
    }
    __syncthreads();
    if (g == 0) {                      // emit valid bitmask (sorted order)
        const float* scb = out + BATCH * KSEL * 4 + b * KSEL;
        #pragma unroll
        for (int w = wv; w < 16; w += 4) {
            int j = w * 64 + lane;
            float s = (j < KSEL) ? scb[j] : -1.0f;
            unsigned long long m = __ballot(s > SCORE_T);
            if (lane == 0) validw[b * 16 + w] = m;
        }
    }
    #pragma unroll
    for (int q = 0; q < 4; ++q) {
        int i = g * 16 + wv * 4 + q;
        if (i >= KSEL) continue;                 // wave-uniform
        float4 bi = sbox[i];
        float  ai = sarea[i];
        int    ci = scls[i];
        uint64_t* dst = supmat + ((size_t)b * 1024 + i) * 16;
        uint32_t nzm = 0;
        #pragma unroll
        for (int w = 0; w < 16; ++w) {
            int j = w * 64 + lane;
            bool sup = false;
            if (j > i && j < KSEL) {
                float4 bj = sbox[j];
                float lx = fmaxf(bi.x, bj.x), ly = fmaxf(bi.y, bj.y);
                float rx = fminf(bi.z, bj.z), ry = fminf(bi.w, bj.w);
                float iw = fmaxf(rx - lx, 0.0f), ih = fmaxf(ry - ly, 0.0f);
                float inter = iw * ih;
                float iou = inter / (ai + sarea[j] - inter + 1e-8f);
                sup = (iou > IOU_T) && (ci == scls[j]);
            }
            unsigned long long m = __ballot(sup);
            if (m) {
                nzm |= 1u << w;
                if (lane == 0) dst[w] = m;
            }
        }
        if (lane == 0) rowmask[(size_t)b * 1024 + i] = (uint16_t)nzm;
    }
}

// ---- sparse greedy scan: one block/image. Build 1024-bit "has suppressors"
// bitmap; a single lane walks only set bits of keep&nz (typically none),
// applying the few real suppression rows. Keep state in LDS. No shfl chain.
__global__ void __launch_bounds__(64) nms_scan_kernel(const uint64_t* __restrict__ supmat,
                                                      const uint16_t* __restrict__ rowmask,
                                                      const uint64_t* __restrict__ validw,
                                                      float* __restrict__ out) {
    __shared__ uint64_t kp[16];
    __shared__ uint64_t nzs[16];
    __shared__ uint16_t rm_lds[1024];
    const int b    = blockIdx.x;
    const int lane = threadIdx.x;
    if (lane < 16) kp[lane] = validw[b * 16 + lane];
    const uint32_t* rm32 = reinterpret_cast<const uint32_t*>(rowmask + (size_t)b * 1024);
    #pragma unroll
    for (int t = lane; t < 512; t += 64) ((uint32_t*)rm_lds)[t] = rm32[t];
    __syncthreads();
    #pragma unroll
    for (int it = 0; it < 16; ++it) {
        int i = it * 64 + lane;
        unsigned long long m = __ballot(rm_lds[i] != 0);
        if (lane == 0) nzs[it] = m;
    }
    __syncthreads();
    if (lane == 0) {
        const uint64_t* rowbase = supmat + (size_t)b * 1024 * 16;
        #pragma unroll 1
        for (int w16 = 0; w16 < 16; ++w16) {
            uint64_t kw   = kp[w16];
            uint64_t nzw  = nzs[w16];
            uint64_t done = 0;
            for (;;) {
                uint64_t cand = kw & nzw & ~done;
                if (!cand) break;
                int bit = __ffsll((unsigned long long)cand) - 1;
                done |= 1ull << bit;
                int i = w16 * 64 + bit;
                uint32_t m = rm_lds[i];
                const uint64_t* r = rowbase + (size_t)i * 16;
                while (m) {
                    int w = __ffs(m) - 1; m &= m - 1;   // w >= w16 (rows have j>i only)
                    uint64_t rv = r[w];
                    uint64_t nk = kp[w] & ~rv;
                    kp[w] = nk;
                    if (w == w16) kw = nk;
                }
            }
        }
    }
    __syncthreads();
    const int keep_off = BATCH * KSEL * 4 + 2 * BATCH * KSEL;
    #pragma unroll
    for (int it = 0; it < 16; ++it) {
        uint64_t kw = kp[it];                    // LDS broadcast
        int j = it * 64 + lane;
        if (j < KSEL)
            out[keep_off + b * KSEL + j] = ((kw >> lane) & 1ull) ? 1.0f : 0.0f;
    }
}

extern "C" void kernel_launch(void* const* d_in, const int* in_sizes, int n_in,
                              void* d_out, int out_size, void* d_ws, size_t ws_size,
                              hipStream_t stream) {
    const float* anchors        = (const float*)d_in[1];
    const float* regression     = (const float*)d_in[2];
    const float* classification = (const float*)d_in[3];
    float* out = (float*)d_out;

    char* ws = (char*)d_ws;
    const size_t BA = (size_t)BATCH * A_NUM;          // 392832 = 3069 * 128
    float*    scores   = (float*)ws;                  // 1,571,328 B
    int*      classes  = (int*)(ws + 1571328);        // 1,571,328 B -> 3,142,656
    uint64_t* selkeys  = (uint64_t*)(ws + 3142656);   // 65,536 B   -> 3,208,192
    uint32_t* prefix1  = (uint32_t*)(ws + 3208192);   // 256 B
    uint32_t* target2  = (uint32_t*)(ws + 3208448);   // 256 B
    uint32_t* thr32    = (uint32_t*)(ws + 3208704);   // 256 B
    int*      counters = (int*)(ws + 3208960);        // 2,048 B (8 x 256B lines)
    uint64_t* validw   = (uint64_t*)(ws + 3211008);   // 1,024 B  -> 3,212,032
    uint64_t* supmat   = (uint64_t*)(ws + 3212032);   // 1,048,576 B -> 4,260,608
    uint32_t* ghist1   = (uint32_t*)(ws + 4260608);   // 2,097,152 B -> 6,357,760
    uint32_t* ghist2   = (uint32_t*)(ws + 6357760);   // 2,097,152 B -> 8,454,912
    uint16_t* rowmask  = (uint16_t*)(ws + 8454912);   // 16,384 B   -> 8,471,296

    score_kernel<<<3069, 256, 0, stream>>>(classification, scores, classes,
                                           (uint4*)ghist1);  // zeroes ghist1+ghist2
    hist_kernel<1><<<BATCH * HBLK, 1024, 0, stream>>>(scores, nullptr, ghist1);
    hscan_kernel<1><<<BATCH, 1024, 0, stream>>>(ghist1, nullptr, nullptr,
                                                prefix1, target2, nullptr, nullptr);
    hist_kernel<2><<<BATCH * HBLK, 1024, 0, stream>>>(scores, prefix1, ghist2);
    hscan_kernel<2><<<BATCH, 1024, 0, stream>>>(ghist2, target2, prefix1,
                                                thr32, nullptr, selkeys, counters);
    compact_kernel<<<dim3(48, BATCH), 1024, 0, stream>>>(scores, thr32, counters, selkeys);
    rank_emit_kernel<<<dim3(4, BATCH), 256, 0, stream>>>(selkeys, scores, classes,
                                                         anchors, regression, out);
    supmat_kernel<<<dim3(63, BATCH), 256, 0, stream>>>(out, supmat, rowmask, validw);
    nms_scan_kernel<<<BATCH, 64, 0, stream>>>(supmat, rowmask, validw, out);
}